// Round 8
// baseline (234.838 us; speedup 1.0000x reference)
//
#include <hip/hip_runtime.h>

#define BB 4
#define CC 256
#define DD 32
#define SS 4096

typedef __bf16 bf16;
typedef __bf16 bf16x8 __attribute__((ext_vector_type(8)));
typedef __bf16 bf16x4 __attribute__((ext_vector_type(4)));
typedef float f32x4 __attribute__((ext_vector_type(4)));
typedef unsigned int u32;
typedef u32 u32x4 __attribute__((ext_vector_type(4)));
typedef unsigned short u16;

// workspace layout (bf16 elements):
//  q:  [2][BB][SS][DD]  off 0         (pos-major, 32 d inner)
//  k:  [2][BB][SS][DD]  off 1048576
//  v:  [2][BB][...]     off 2097152   chunked B-frag order: V[c][key] at
//       (2*(key>>6) + ks)*8192 + (c>>4)*512 + (quadf*16 + (c&15))*8 + j
//       where kk=key&63, ks=kk>>5, quadf=(kk>>2)&3, j=((kk>>4)&1)*4 + (kk&3)
//       -> each 1 KB fragment is lane-contiguous (lane*16 B), each 32 KB
//       chunk (64 keys x 256 c) is fully contiguous for linear LDS staging.
//  wb: [320][CC]        off 10485760  (bf16 Wq|Wk|Wv stacked)
#define Q_OFF  0
#define K_OFF  1048576
#define V_OFF  2097152
#define WB_OFF 10485760
#define CH_ELEM 16384   // elements per 64-key V chunk (32 KB)

static __device__ __forceinline__ u32 pack2(float lo, float hi) {
    bf16 a = (bf16)lo, b = (bf16)hi;
    u16 ua = __builtin_bit_cast(u16, a), ub = __builtin_bit_cast(u16, b);
    return (u32)ua | ((u32)ub << 16);
}

// LDS-only barrier: drain ds ops, sync, but let global loads stay in flight
static __device__ __forceinline__ void bar_lds() {
    asm volatile("s_waitcnt lgkmcnt(0)" ::: "memory");
    __builtin_amdgcn_s_barrier();
    asm volatile("" ::: "memory");
}

// staged-buffer barrier: wait until only the 12 newest VMEM ops (next chunk's
// 8 staging + the K prefetch quad) remain in flight -> current chunk's staging
// complete, pipeline never drained (T4 counted-vmcnt).
static __device__ __forceinline__ void bar_vm12() {
    asm volatile("s_waitcnt vmcnt(12)" ::: "memory");
    __builtin_amdgcn_s_barrier();
    asm volatile("" ::: "memory");
}
static __device__ __forceinline__ void bar_plain() {
    asm volatile("" ::: "memory");
    __builtin_amdgcn_s_barrier();
    asm volatile("" ::: "memory");
}

// ------------------------------------------------- W fp32 -> bf16 [320][256]
__global__ __launch_bounds__(256) void convert_w_kernel(
    const float* __restrict__ Wq, const float* __restrict__ Wk,
    const float* __restrict__ Wv, bf16* __restrict__ wb)
{
    const int gid = blockIdx.x*256 + threadIdx.x;    // 40 blocks -> 10240
    const int idx = gid*8;
    const int o = idx >> 8, cc = idx & 255;
    const float* row = (o < 32) ? (Wq + (size_t)o*CC)
                     : (o < 64) ? (Wk + (size_t)(o-32)*CC)
                                : (Wv + (size_t)(o-64)*CC);
    const float4 a = *(const float4*)(row + cc);
    const float4 c = *(const float4*)(row + cc + 4);
    bf16x8 pk;
    pk[0]=(bf16)a.x; pk[1]=(bf16)a.y; pk[2]=(bf16)a.z; pk[3]=(bf16)a.w;
    pk[4]=(bf16)c.x; pk[5]=(bf16)c.y; pk[6]=(bf16)c.z; pk[7]=(bf16)c.w;
    *(bf16x8*)(wb + idx) = pk;
}

// ------------------------------------------------- fused q,k,v projection (MFMA)
// C[pos][o] = sum_cc X[cc][pos]*W[o][cc] + bias;  o: 0-31 q, 32-63 k, 64-319 v
// V written in attn's chunked B-frag order (see workspace comment).
__global__ __launch_bounds__(256, 2) void proj_all_kernel(
    const float* __restrict__ x, const float* __restrict__ y,
    const bf16* __restrict__ wb,
    const float* __restrict__ bq, const float* __restrict__ bk,
    const float* __restrict__ bv,
    bf16* __restrict__ qout, bf16* __restrict__ kout, bf16* __restrict__ vout)
{
    // xT: [2][64 pos][40 bf16] (row 80 B, 16B-aligned)
    __shared__ __align__(16) char smem[2*5120];
    bf16* xT  = (bf16*)smem;
    u32*  xTw = (u32*)smem;

    const int t    = threadIdx.x;
    const int lane = t & 63;
    const int w    = t >> 6;
    const int ln   = lane & 15;
    const int quad = lane >> 4;

    const int bid  = blockIdx.x;
    const int dirb = bid & 7;
    const int src  = dirb >> 2;
    const int b    = dirb & 3;
    const int i0   = (bid >> 3) * 64;
    const float* in = src ? y : x;
    const float* xbase = in + (size_t)b*CC*SS + i0;

    const int cp = t >> 4;            // cc-pair 0..15 -> cc {2cp, 2cp+1}
    const int pq = (t & 15) * 4;      // pos 0..60

    float bias[5];
    #pragma unroll
    for (int nbl = 0; nbl < 5; ++nbl) {
        const int o = 80*w + nbl*16 + ln;
        bias[nbl] = (o < 32) ? bq[o] : (o < 64) ? bk[o-32] : bv[o-64];
    }
    f32x4 acc[4][5];
    #pragma unroll
    for (int mb = 0; mb < 4; ++mb)
        #pragma unroll
        for (int nbl = 0; nbl < 5; ++nbl)
            acc[mb][nbl] = (f32x4){bias[nbl], bias[nbl], bias[nbl], bias[nbl]};

    const bf16* wrow = wb + (size_t)(80*w + ln)*CC + quad*8;
    bf16x8 bf[5];
    #pragma unroll
    for (int nbl = 0; nbl < 5; ++nbl)
        bf[nbl] = *(const bf16x8*)(wrow + (size_t)nbl*16*CC);

    // stage chunk 0 into buf0
    {
        const float* r0 = xbase + (size_t)(2*cp)*SS + pq;
        const float4 a0 = *(const float4*)r0;
        const float4 a1 = *(const float4*)(r0 + SS);
        xTw[(pq+0)*20 + cp] = pack2(a0.x, a1.x);
        xTw[(pq+1)*20 + cp] = pack2(a0.y, a1.y);
        xTw[(pq+2)*20 + cp] = pack2(a0.z, a1.z);
        xTw[(pq+3)*20 + cp] = pack2(a0.w, a1.w);
    }
    // prefetch chunk 1 into regs
    float4 a0, a1;
    {
        const float* r1 = xbase + (size_t)(32 + 2*cp)*SS + pq;
        a0 = *(const float4*)r1;
        a1 = *(const float4*)(r1 + SS);
    }
    bar_lds();

    for (int n = 0; n < 8; ++n) {
        bf16x8 af[4];
        #pragma unroll
        for (int mb = 0; mb < 4; ++mb)
            af[mb] = *(const bf16x8*)(xT + (n&1)*2560 + (mb*16 + ln)*40 + quad*8);
        // write prefetched chunk n+1 into other buffer
        if (n < 7) {
            u32* dst = xTw + ((n+1)&1)*1280;
            dst[(pq+0)*20 + cp] = pack2(a0.x, a1.x);
            dst[(pq+1)*20 + cp] = pack2(a0.y, a1.y);
            dst[(pq+2)*20 + cp] = pack2(a0.z, a1.z);
            dst[(pq+3)*20 + cp] = pack2(a0.w, a1.w);
        }
        // prefetch chunk n+2 regs (wrap keeps loads in-bounds; redundant at tail)
        {
            const int cc2 = ((n+2)*32) & 255;
            const float* r2 = xbase + (size_t)(cc2 + 2*cp)*SS + pq;
            a0 = *(const float4*)r2;
            a1 = *(const float4*)(r2 + SS);
        }
        #pragma unroll
        for (int mb = 0; mb < 4; ++mb)
            #pragma unroll
            for (int nbl = 0; nbl < 5; ++nbl)
                acc[mb][nbl] = __builtin_amdgcn_mfma_f32_16x16x32_bf16(
                                   af[mb], bf[nbl], acc[mb][nbl], 0, 0, 0);
        // prefetch next W chunk
        const int ccn = ((n+1)*32) & 255;
        #pragma unroll
        for (int nbl = 0; nbl < 5; ++nbl)
            bf[nbl] = *(const bf16x8*)(wrow + (size_t)nbl*16*CC + ccn);
        bar_lds();
    }

    bf16* qo = qout + (size_t)(src*BB + b)*SS*DD;
    bf16* ko = kout + (size_t)(src*BB + b)*SS*DD;
    bf16* vo = vout + (size_t)(src*BB + b)*CC*SS;
    const int n0 = i0 >> 6;
    #pragma unroll
    for (int nbl = 0; nbl < 5; ++nbl) {
        const int o = 80*w + nbl*16 + ln;
        if (o < 32) {
            #pragma unroll
            for (int mb = 0; mb < 4; ++mb)
                #pragma unroll
                for (int r = 0; r < 4; ++r)
                    qo[(size_t)(i0 + mb*16 + quad*4 + r)*DD + o] = (bf16)acc[mb][nbl][r];
        } else if (o < 64) {
            #pragma unroll
            for (int mb = 0; mb < 4; ++mb)
                #pragma unroll
                for (int r = 0; r < 4; ++r)
                    ko[(size_t)(i0 + mb*16 + quad*4 + r)*DD + (o-32)] = (bf16)acc[mb][nbl][r];
        } else {
            const int c = o - 64;
            const int cb = c >> 4, cl = c & 15;
            // pos = i0+mb*16+quad*4+r -> chunk n0, ks=mb>>1, j=(mb&1)*4+r,
            // quadf=quad -> contiguous bf16x4 store within lane's 16B slot
            #pragma unroll
            for (int mb = 0; mb < 4; ++mb) {
                bf16x4 pk;
                #pragma unroll
                for (int r = 0; r < 4; ++r) pk[r] = (bf16)acc[mb][nbl][r];
                *(bf16x4*)(vo + (size_t)(2*n0 + (mb>>1))*8192 + cb*512
                              + (quad*16 + cl)*8 + (mb&1)*4) = pk;
            }
        }
    }
}

// ------------------------------------------------- attention (key-parity waves)
// Block: 64 q x 256 c, grid 512 (2 blocks/CU). Wave (qh = w>>1, kh = (w^bid)&1)
// owns queries [i0+32qh,+32) x all 256 c x chunks of parity kh. Per iter n:
// the kh==n&1 wave-pair does PV(n) (each ds_read_b128 feeds TWO MFMAs -> LDS
// read traffic HALVED vs R7, the measured binding pipe), while the other pair
// computes S^T(n+1)+softmax between the SAME barriers (enforced phase
// interleave; kh^=bid decorrelates the two co-resident blocks). P private in
// regs (verified pack); V staged by global_load_lds DMA, double-buffered,
// vmcnt(12) counted-wait (8 stage + 4 K stay in flight; issue pattern kept
// symmetric at the tail via wrapped dummy S^T with lpq guard). kh-pairs merge
// o/l via a 2-pass LDS reduction reusing vsm after a one-time vmcnt(0) drain.
#define L2E   1.4426950408889634f
#define SM_C  (16.0f * L2E)

__global__ __launch_bounds__(256, 2) void attn_kernel(
    const bf16* __restrict__ qg, const bf16* __restrict__ kg,
    const bf16* __restrict__ vg, float* __restrict__ out)
{
    __shared__ __align__(16) char vsm[2*32768];   // V dbuf; epilogue: o_s[32][257] f32
    __shared__ float l_s[2][64];

    const int t    = threadIdx.x;
    const int lane = t & 63;
    const int w    = t >> 6;
    const int ln   = lane & 15;
    const int quad = lane >> 4;

    const int bid  = blockIdx.x;
    const int dirb = bid & 7;              // one (dir,b) per XCD -> K/V L2-resident
    const int dir  = dirb >> 2;
    const int b    = dirb & 3;
    const int i0   = (bid >> 3) * 64;
    const int qh   = w >> 1;
    const int kh   = (w ^ bid) & 1;

    const bf16* q = qg + ((size_t)dir*BB + b)*SS*DD;
    const bf16* k = kg + ((size_t)(1-dir)*BB + b)*SS*DD;
    const bf16* v = vg + ((size_t)(1-dir)*BB + b)*(size_t)CC*SS;
    float* op = out + ((size_t)dir*BB + b)*(size_t)CC*SS;

    // Q B-frags (wave's 32 queries, 2 tiles)
    const bf16x8 bq0 = *(const bf16x8*)(q + (size_t)(i0 + qh*32 +      ln)*DD + quad*8);
    const bf16x8 bq1 = *(const bf16x8*)(q + (size_t)(i0 + qh*32 + 16 + ln)*DD + quad*8);
    // K A-frag base: A[m=key(ln)][k=d(quad*8+)]
    const bf16* kbase = k + (size_t)ln*DD + quad*8;
    // staging: thread copies 8x16B, linear
    const bf16* vstage = v + w*512 + lane*8;
    char* lds0 = vsm + w*1024;

    f32x4 o0[16], o1[16];
    #pragma unroll
    for (int cb = 0; cb < 16; ++cb) {
        o0[cb] = (f32x4){0.f,0.f,0.f,0.f};
        o1[cb] = (f32x4){0.f,0.f,0.f,0.f};
    }
    f32x4 lpq0 = (f32x4){0.f,0.f,0.f,0.f};
    f32x4 lpq1 = (f32x4){0.f,0.f,0.f,0.f};

    bf16x8 kf[4];
    #pragma unroll
    for (int nb = 0; nb < 4; ++nb)
        kf[nb] = *(const bf16x8*)(kbase + (size_t)(kh*64 + nb*16)*DD);

    #define STAGE(ch, buf) do {                                               \
        const bf16* gp_ = vstage + (size_t)(ch)*CH_ELEM;                      \
        char* lp_ = lds0 + (buf)*32768;                                       \
        _Pragma("unroll")                                                     \
        for (int j = 0; j < 8; ++j)                                           \
            __builtin_amdgcn_global_load_lds(                                 \
                (const __attribute__((address_space(1))) void*)(gp_ + j*2048),\
                (__attribute__((address_space(3))) void*)(lp_ + j*4096),      \
                16, 0, 0);                                                    \
    } while (0)

    // dual-q softmax: s0/s1 -> pa0/pa1; lpq guarded by g (0 on wrapped dummy)
    #define SMAX2(g) do {                                                     \
        float e0_[4][4], e1_[4][4];                                           \
        _Pragma("unroll")                                                     \
        for (int nb = 0; nb < 4; ++nb)                                        \
            _Pragma("unroll")                                                 \
            for (int r = 0; r < 4; ++r) {                                     \
                e0_[nb][r] = exp2f(s0[nb][r]*L2E - SM_C);                      \
                e1_[nb][r] = exp2f(s1[nb][r]*L2E - SM_C);                      \
                lpq0[r] = fmaf((g), e0_[nb][r], lpq0[r]);                     \
                lpq1[r] = fmaf((g), e1_[nb][r], lpq1[r]);                     \
            }                                                                 \
        _Pragma("unroll")                                                     \
        for (int ks = 0; ks < 2; ++ks) {                                      \
            u32x4 p0_, p1_;                                                   \
            _Pragma("unroll")                                                 \
            for (int jp = 0; jp < 4; ++jp) {                                  \
                p0_[jp] = pack2(e0_[2*ks + (jp>>1)][2*(jp&1)],                \
                                e0_[2*ks + (jp>>1)][2*(jp&1) + 1]);           \
                p1_[jp] = pack2(e1_[2*ks + (jp>>1)][2*(jp&1)],                \
                                e1_[2*ks + (jp>>1)][2*(jp&1) + 1]);           \
            }                                                                 \
            pa0[ks] = __builtin_bit_cast(bf16x8, p0_);                        \
            pa1[ks] = __builtin_bit_cast(bf16x8, p1_);                        \
        }                                                                     \
    } while (0)

    bf16x8 pa0[2], pa1[2];
    // prologue: stage chunks 0,1; kh==0 computes pa(0) now, then kf <- K(2)
    STAGE(0, 0);
    STAGE(1, 1);
    if (kh == 0) {
        f32x4 s0[4], s1[4];
        #pragma unroll
        for (int nb = 0; nb < 4; ++nb) {
            s0[nb] = __builtin_amdgcn_mfma_f32_16x16x32_bf16(
                         kf[nb], bq0, (f32x4){0.f,0.f,0.f,0.f}, 0, 0, 0);
            s1[nb] = __builtin_amdgcn_mfma_f32_16x16x32_bf16(
                         kf[nb], bq1, (f32x4){0.f,0.f,0.f,0.f}, 0, 0, 0);
        }
        #pragma unroll
        for (int nb = 0; nb < 4; ++nb)
            kf[nb] = *(const bf16x8*)(kbase + (size_t)(128 + nb*16)*DD);
        SMAX2(1.0f);
    }

    for (int n = 0; n < 64; ++n) {
        bar_vm12();   // staging(n) complete on all threads; 12 newest in flight
        if ((n & 1) == kh) {
            // PV(n): 32 ds_read_b128, each feeds 2 MFMAs (q-tiles)
            const char* bufp = vsm + (n & 1)*32768;
            __builtin_amdgcn_s_setprio(1);
            #pragma unroll
            for (int st = 0; st < 32; ++st) {
                const int cb = st & 15;          // ks = st>>4
                const bf16x8 vfr = *(const bf16x8*)(bufp + st*1024 + lane*16);
                o0[cb] = __builtin_amdgcn_mfma_f32_16x16x32_bf16(
                             pa0[st >> 4], vfr, o0[cb], 0, 0, 0);
                o1[cb] = __builtin_amdgcn_mfma_f32_16x16x32_bf16(
                             pa1[st >> 4], vfr, o1[cb], 0, 0, 0);
            }
            __builtin_amdgcn_s_setprio(0);
        } else {
            // S^T((n+1)&63) + softmax -> pa (runs under the other pair's PV);
            // wrapped dummy at n=63 keeps vmcnt pattern symmetric (g=0)
            f32x4 s0[4], s1[4];
            #pragma unroll
            for (int nb = 0; nb < 4; ++nb) {
                s0[nb] = __builtin_amdgcn_mfma_f32_16x16x32_bf16(
                             kf[nb], bq0, (f32x4){0.f,0.f,0.f,0.f}, 0, 0, 0);
                s1[nb] = __builtin_amdgcn_mfma_f32_16x16x32_bf16(
                             kf[nb], bq1, (f32x4){0.f,0.f,0.f,0.f}, 0, 0, 0);
            }
            const int j3 = ((n + 3) & 63) * 64;
            #pragma unroll
            for (int nb = 0; nb < 4; ++nb)
                kf[nb] = *(const bf16x8*)(kbase + (size_t)(j3 + nb*16)*DD);
            const float g = (n < 63) ? 1.0f : 0.0f;
            SMAX2(g);
        }
        bar_plain();                 // all readers of buf[n&1] done
        STAGE((n + 2) & 63, n & 1);  // refill freed buffer (wrapped at tail)
    }

    // drain stray tail DMAs before reusing vsm as the reduction buffer
    asm volatile("s_waitcnt vmcnt(0)" ::: "memory");
    __builtin_amdgcn_s_barrier();

    // per-wave l: lane ln = q-col, keys {16nb+4quad+r}: fold r, reduce quads
    float lp0 = (lpq0[0] + lpq0[1]) + (lpq0[2] + lpq0[3]);
    float lp1 = (lpq1[0] + lpq1[1]) + (lpq1[2] + lpq1[3]);
    lp0 += __shfl_xor(lp0, 16); lp0 += __shfl_xor(lp0, 32);
    lp1 += __shfl_xor(lp1, 16); lp1 += __shfl_xor(lp1, 32);
    if (quad == 0) {
        l_s[kh][qh*32 +      ln] = lp0;
        l_s[kh][qh*32 + 16 + ln] = lp1;
    }

    // kh-pair reduction, one qh per pass; o_s[32][257] f32 (2-way banks, free)
    float* o_s = (float*)vsm;
    #pragma unroll
    for (int ph = 0; ph < 2; ++ph) {
        if (kh == 0 && qh == ph) {
            #pragma unroll
            for (int cb = 0; cb < 16; ++cb) {
                const int c = cb*16 + ln;
                #pragma unroll
                for (int r = 0; r < 4; ++r) {
                    o_s[(quad*4 + r)*257 + c]      = o0[cb][r];
                    o_s[(16 + quad*4 + r)*257 + c] = o1[cb][r];
                }
            }
        }
        bar_lds();
        if (kh == 1 && qh == ph) {
            #pragma unroll
            for (int qb = 0; qb < 2; ++qb) {
                const int q0 = qh*32 + qb*16 + quad*4;
                f32x4 ri;
                #pragma unroll
                for (int r = 0; r < 4; ++r)
                    ri[r] = 1.0f / (l_s[0][q0 + r] + l_s[1][q0 + r]);
                #pragma unroll
                for (int cb = 0; cb < 16; ++cb) {
                    const int c = cb*16 + ln;
                    const int row = qb*16 + quad*4;
                    const f32x4 mine = qb ? o1[cb] : o0[cb];
                    float4 val;
                    val.x = (mine[0] + o_s[(row+0)*257 + c]) * ri[0];
                    val.y = (mine[1] + o_s[(row+1)*257 + c]) * ri[1];
                    val.z = (mine[2] + o_s[(row+2)*257 + c]) * ri[2];
                    val.w = (mine[3] + o_s[(row+3)*257 + c]) * ri[3];
                    *(float4*)(op + (size_t)c*SS + i0 + q0) = val;
                }
            }
        }
        bar_lds();
    }
    #undef STAGE
    #undef SMAX2
}

// ------------------------------------------------- launch
extern "C" void kernel_launch(void* const* d_in, const int* in_sizes, int n_in,
                              void* d_out, int out_size, void* d_ws, size_t ws_size,
                              hipStream_t stream)
{
    const float* x  = (const float*)d_in[0];
    const float* y  = (const float*)d_in[1];
    const float* Wq = (const float*)d_in[2];
    const float* bq = (const float*)d_in[3];
    const float* Wk = (const float*)d_in[4];
    const float* bk = (const float*)d_in[5];
    const float* Wv = (const float*)d_in[6];
    const float* bv = (const float*)d_in[7];
    float* out = (float*)d_out;
    bf16* ws   = (bf16*)d_ws;

    bf16* qw = ws + Q_OFF;
    bf16* kw = ws + K_OFF;
    bf16* vw = ws + V_OFF;
    bf16* wb = ws + WB_OFF;

    convert_w_kernel<<<40,  256, 0, stream>>>(Wq, Wk, Wv, wb);
    proj_all_kernel <<<512, 256, 0, stream>>>(x, y, wb, bq, bk, bv, qw, kw, vw);
    attn_kernel     <<<512, 256, 0, stream>>>(qw, kw, vw, out);
}

// Round 10
// 222.819 us; speedup vs baseline: 1.0539x; 1.0539x over previous
//
#include <hip/hip_runtime.h>

#define BB 4
#define CC 256
#define DD 32
#define SS 4096

typedef __bf16 bf16;
typedef __bf16 bf16x8 __attribute__((ext_vector_type(8)));
typedef __bf16 bf16x4 __attribute__((ext_vector_type(4)));
typedef float f32x4 __attribute__((ext_vector_type(4)));
typedef unsigned int u32;
typedef u32 u32x4 __attribute__((ext_vector_type(4)));
typedef unsigned short u16;

// workspace layout (bf16 elements):
//  q:  [2][BB][SS][DD]  off 0         (pos-major, 32 d inner)
//  k:  [2][BB][SS][DD]  off 1048576
//  v:  [2][BB][...]     off 2097152   chunked B-frag order: V[c][key] at
//       (2*(key>>6) + ks)*8192 + (c>>4)*512 + (quadf*16 + (c&15))*8 + j
//       (kk=key&63, ks=kk>>5, quadf=(kk>>2)&3, j=((kk>>4)&1)*4+(kk&3));
//       each 1 KB fragment lane-contiguous; each 32 KB chunk contiguous.
//       TRANSIENT ALIAS: transpose_x writes X^T A-frag tiles here first;
//       proj block (dirb,tile) DMA-reads slice [tile*16384,+16384) into LDS,
//       then overwrites exactly that slice with V output (slice-exact, safe).
//  wb: [320][CC]        off 10485760  (bf16 Wq|Wk|Wv stacked)
#define Q_OFF  0
#define K_OFF  1048576
#define V_OFF  2097152
#define WB_OFF 10485760
#define CH_ELEM 16384   // elements per 64-key V chunk / per X^T tile (32 KB)

static __device__ __forceinline__ u32 pack2(float lo, float hi) {
    bf16 a = (bf16)lo, b = (bf16)hi;
    u16 ua = __builtin_bit_cast(u16, a), ub = __builtin_bit_cast(u16, b);
    return (u32)ua | ((u32)ub << 16);
}

// staged-buffer barrier: wait until only the 12 newest VMEM ops (next chunk's
// 8 staging + the K prefetch quad) remain in flight (T4 counted-vmcnt).
static __device__ __forceinline__ void bar_vm12() {
    asm volatile("s_waitcnt vmcnt(12)" ::: "memory");
    __builtin_amdgcn_s_barrier();
    asm volatile("" ::: "memory");
}
static __device__ __forceinline__ void bar_plain() {
    asm volatile("" ::: "memory");
    __builtin_amdgcn_s_barrier();
    asm volatile("" ::: "memory");
}

// ------------------------------------------------- W fp32 -> bf16 [320][256]
__global__ __launch_bounds__(256) void convert_w_kernel(
    const float* __restrict__ Wq, const float* __restrict__ Wk,
    const float* __restrict__ Wv, bf16* __restrict__ wb)
{
    const int gid = blockIdx.x*256 + threadIdx.x;    // 40 blocks -> 10240
    const int idx = gid*8;
    const int o = idx >> 8, cc = idx & 255;
    const float* row = (o < 32) ? (Wq + (size_t)o*CC)
                     : (o < 64) ? (Wk + (size_t)(o-32)*CC)
                                : (Wv + (size_t)(o-64)*CC);
    const float4 a = *(const float4*)(row + cc);
    const float4 c = *(const float4*)(row + cc + 4);
    bf16x8 pk;
    pk[0]=(bf16)a.x; pk[1]=(bf16)a.y; pk[2]=(bf16)a.z; pk[3]=(bf16)a.w;
    pk[4]=(bf16)c.x; pk[5]=(bf16)c.y; pk[6]=(bf16)c.z; pk[7]=(bf16)c.w;
    *(bf16x8*)(wb + idx) = pk;
}

// ------------------------------------------------- X fp32 -> bf16 X^T A-frag tiles
// Writes element (pos, cc) of (src,b) at xb_base + tile*16384 + (pos>>4)*4096
// + (cc>>5)*512 + ((cc>>3)&3)*128 + (pos&15)*8 + (cc&7)  (pos within tile)
// -> proj's A-frag (m=pos low4, k=cc within 32-chunk) is lane*16B contiguous.
// Memory-bound, no barriers; reads float4-coalesced along pos.
__global__ __launch_bounds__(256) void transpose_x_kernel(
    const float* __restrict__ x, const float* __restrict__ y,
    bf16* __restrict__ xb)
{
    const int t    = threadIdx.x;
    const int bid  = blockIdx.x;
    const int dirb = bid & 7;
    const int src  = dirb >> 2;
    const int b    = dirb & 3;
    const int tile = bid >> 3;                    // 0..63
    const float* in = (src ? y : x) + (size_t)b*CC*SS;
    bf16* outp = xb + (size_t)dirb*1048576 + (size_t)tile*CH_ELEM;

    const int pg = t & 15;          // pos = tile*64 + pg*4 + p
    const int cg = t >> 4;          // cc0 = outer*128 + cg*8
    #pragma unroll
    for (int outer = 0; outer < 2; ++outer) {
        const int cc0 = outer*128 + cg*8;
        float4 v4[8];
        #pragma unroll
        for (int j = 0; j < 8; ++j)
            v4[j] = *(const float4*)(in + (size_t)(cc0 + j)*SS + tile*64 + pg*4);
        #pragma unroll
        for (int p = 0; p < 4; ++p) {
            const int pos = pg*4 + p;             // within tile
            bf16x8 pk;
            #pragma unroll
            for (int j = 0; j < 8; ++j) {
                const float fv = (p==0)?v4[j].x:(p==1)?v4[j].y:(p==2)?v4[j].z:v4[j].w;
                pk[j] = (bf16)fv;
            }
            *(bf16x8*)(outp + (pos>>4)*4096 + (cc0>>5)*512
                       + ((cc0>>3)&3)*128 + (pos&15)*8) = pk;
        }
    }
}

// ------------------------------------------------- fused q,k,v projection (MFMA)
// C[pos][o] = sum_cc X[cc][pos]*W[o][cc] + bias;  o: 0-31 q, 32-63 k, 64-319 v
// X^T tile (64 pos x 256 cc, A-frag order) DMA-staged to LDS in one shot
// (global_load_lds x8/thread), ONE barrier, then 8 chunks x 20 MFMA per wave
// straight through (conflict-free ds_read_b128, W prefetched from L2).
// Reads its xb slice from the V region and overwrites the SAME slice with V.
__global__ __launch_bounds__(256, 2) void proj_all_kernel(
    const bf16* __restrict__ xb, const bf16* __restrict__ wb,
    const float* __restrict__ bq, const float* __restrict__ bk,
    const float* __restrict__ bv,
    bf16* __restrict__ qout, bf16* __restrict__ kout, bf16* __restrict__ vout)
{
    __shared__ __align__(16) char xsm[32768];

    const int t    = threadIdx.x;
    const int lane = t & 63;
    const int w    = t >> 6;
    const int ln   = lane & 15;
    const int quad = lane >> 4;

    const int bid  = blockIdx.x;
    const int dirb = bid & 7;
    const int src  = dirb >> 2;
    const int b    = dirb & 3;
    const int tile = bid >> 3;
    const int i0   = tile * 64;

    // DMA stage the whole X^T tile (32 KB, linear)
    {
        const bf16* xstage = xb + (size_t)dirb*1048576 + (size_t)tile*CH_ELEM
                             + w*512 + lane*8;
        char* ldsb = xsm + w*1024;
        #pragma unroll
        for (int j = 0; j < 8; ++j)
            __builtin_amdgcn_global_load_lds(
                (const __attribute__((address_space(1))) void*)(xstage + j*2048),
                (__attribute__((address_space(3))) void*)(ldsb + j*4096),
                16, 0, 0);
    }

    float bias[5];
    #pragma unroll
    for (int nbl = 0; nbl < 5; ++nbl) {
        const int o = 80*w + nbl*16 + ln;
        bias[nbl] = (o < 32) ? bq[o] : (o < 64) ? bk[o-32] : bv[o-64];
    }
    const bf16* wrow = wb + (size_t)(80*w + ln)*CC + quad*8;
    bf16x8 bf[5];
    #pragma unroll
    for (int nbl = 0; nbl < 5; ++nbl)
        bf[nbl] = *(const bf16x8*)(wrow + (size_t)nbl*16*CC);   // FIX: R9 dropped the nbl*16*CC offset

    f32x4 acc[4][5];
    #pragma unroll
    for (int mb = 0; mb < 4; ++mb)
        #pragma unroll
        for (int nbl = 0; nbl < 5; ++nbl)
            acc[mb][nbl] = (f32x4){bias[nbl], bias[nbl], bias[nbl], bias[nbl]};

    __syncthreads();   // DMA complete (vmcnt(0) drain is fine here: one-shot)

    for (int n = 0; n < 8; ++n) {
        bf16x8 af[4];
        #pragma unroll
        for (int mb = 0; mb < 4; ++mb)
            af[mb] = *(const bf16x8*)(xsm + mb*8192 + n*1024 + lane*16);
        #pragma unroll
        for (int mb = 0; mb < 4; ++mb)
            #pragma unroll
            for (int nbl = 0; nbl < 5; ++nbl)
                acc[mb][nbl] = __builtin_amdgcn_mfma_f32_16x16x32_bf16(
                                   af[mb], bf[nbl], acc[mb][nbl], 0, 0, 0);
        // prefetch next W chunk (wrap at tail: redundant, in-bounds)
        const int ccn = ((n+1)*32) & 255;
        #pragma unroll
        for (int nbl = 0; nbl < 5; ++nbl)
            bf[nbl] = *(const bf16x8*)(wrow + (size_t)nbl*16*CC + ccn);
    }

    bf16* qo = qout + (size_t)(src*BB + b)*SS*DD;
    bf16* ko = kout + (size_t)(src*BB + b)*SS*DD;
    bf16* vo = vout + (size_t)(src*BB + b)*CC*SS;
    const int n0 = tile;
    #pragma unroll
    for (int nbl = 0; nbl < 5; ++nbl) {
        const int o = 80*w + nbl*16 + ln;
        if (o < 32) {
            #pragma unroll
            for (int mb = 0; mb < 4; ++mb)
                #pragma unroll
                for (int r = 0; r < 4; ++r)
                    qo[(size_t)(i0 + mb*16 + quad*4 + r)*DD + o] = (bf16)acc[mb][nbl][r];
        } else if (o < 64) {
            #pragma unroll
            for (int mb = 0; mb < 4; ++mb)
                #pragma unroll
                for (int r = 0; r < 4; ++r)
                    ko[(size_t)(i0 + mb*16 + quad*4 + r)*DD + (o-32)] = (bf16)acc[mb][nbl][r];
        } else {
            const int c = o - 64;
            const int cb = c >> 4, cl = c & 15;
            // pos = i0+mb*16+quad*4+r -> chunk n0, ks=mb>>1, j=(mb&1)*4+r,
            // quadf=quad -> contiguous bf16x4 store within lane's 16B slot
            #pragma unroll
            for (int mb = 0; mb < 4; ++mb) {
                bf16x4 pk;
                #pragma unroll
                for (int r = 0; r < 4; ++r) pk[r] = (bf16)acc[mb][nbl][r];
                *(bf16x4*)(vo + (size_t)(2*n0 + (mb>>1))*8192 + cb*512
                              + (quad*16 + cl)*8 + (mb&1)*4) = pk;
            }
        }
    }
}

// ------------------------------------------------- attention (LDS-staged V, private P)
// R7 verified structure (127 us, MfmaUtil 26%, 0 conflicts, VGPR 88).
// Block: 64 q x 256 c, grid 512 (2 blocks/CU). Wave w privately owns queries
// [i0+16w,+16) x all 256 c x all keys: S^T+softmax+P all in registers, NO
// cross-wave reduction. V delivered by bulk async DMA (32 KB chunk,
// pre-permuted lane-contiguous), double-buffered; vmcnt(12) counted barrier
// keeps next chunk's staging + K prefetch in flight (never drains).
#define L2E   1.4426950408889634f
#define SM_C  (16.0f * L2E)

__global__ __launch_bounds__(256, 2) void attn_kernel(
    const bf16* __restrict__ qg, const bf16* __restrict__ kg,
    const bf16* __restrict__ vg, float* __restrict__ out)
{
    __shared__ __align__(16) char vsm[2*32768];   // V chunk double buffer

    const int t    = threadIdx.x;
    const int lane = t & 63;
    const int w    = t >> 6;
    const int ln   = lane & 15;
    const int quad = lane >> 4;

    const int bid  = blockIdx.x;
    const int dirb = bid & 7;              // one (dir,b) per XCD -> V L2-resident
    const int dir  = dirb >> 2;
    const int b    = dirb & 3;
    const int i0   = (bid >> 3) * 64;

    const bf16* q = qg + ((size_t)dir*BB + b)*SS*DD;
    const bf16* k = kg + ((size_t)(1-dir)*BB + b)*SS*DD;
    const bf16* v = vg + ((size_t)(1-dir)*BB + b)*(size_t)CC*SS;
    float* op = out + ((size_t)dir*BB + b)*(size_t)CC*SS;

    // Q B-frag: B[n=q(ln)][k=d(quad*8+)] — wave's 16 queries
    const bf16x8 bq = *(const bf16x8*)(q + (size_t)(i0 + w*16 + ln)*DD + quad*8);
    // K A-frag base: A[m=key(ln)][k=d(quad*8+)]
    const bf16* kbase = k + (size_t)ln*DD + quad*8;
    // staging: thread t copies 8x16B, linear
    const bf16* vstage = v + w*512 + lane*8;
    char* lds0 = vsm + w*1024;

    f32x4 o[16];
    #pragma unroll
    for (int cb = 0; cb < 16; ++cb) o[cb] = (f32x4){0.f,0.f,0.f,0.f};
    f32x4 lpq = (f32x4){0.f,0.f,0.f,0.f};

    bf16x8 kf[4];
    #pragma unroll
    for (int nb = 0; nb < 4; ++nb)
        kf[nb] = *(const bf16x8*)(kbase + (size_t)(nb*16)*DD);

    #define STAGE(ch, buf) do {                                               \
        const bf16* gp_ = vstage + (size_t)(ch)*CH_ELEM;                      \
        char* lp_ = lds0 + (buf)*32768;                                       \
        _Pragma("unroll")                                                     \
        for (int j = 0; j < 8; ++j)                                           \
            __builtin_amdgcn_global_load_lds(                                 \
                (const __attribute__((address_space(1))) void*)(gp_ + j*2048),\
                (__attribute__((address_space(3))) void*)(lp_ + j*4096),      \
                16, 0, 0);                                                    \
    } while (0)

    #define SMAX(sarr, pa) do {                                               \
        float e_[4][4];                                                       \
        _Pragma("unroll")                                                     \
        for (int nb = 0; nb < 4; ++nb)                                        \
            _Pragma("unroll")                                                 \
            for (int r = 0; r < 4; ++r) {                                     \
                e_[nb][r] = exp2f((sarr)[nb][r]*L2E - SM_C);                   \
                lpq[r] += e_[nb][r];                                          \
            }                                                                 \
        _Pragma("unroll")                                                     \
        for (int ks = 0; ks < 2; ++ks) {                                      \
            u32x4 pk_;                                                        \
            _Pragma("unroll")                                                 \
            for (int jp = 0; jp < 4; ++jp)                                    \
                pk_[jp] = pack2(e_[2*ks + (jp>>1)][2*(jp&1)],                 \
                                e_[2*ks + (jp>>1)][2*(jp&1) + 1]);            \
            (pa)[ks] = __builtin_bit_cast(bf16x8, pk_);                       \
        }                                                                     \
    } while (0)

    bf16x8 paA[2], paB[2];
    // prologue: S^T(0) -> paA; stage chunks 0,1; kf <- K(1)
    {
        f32x4 s[4];
        #pragma unroll
        for (int nb = 0; nb < 4; ++nb)
            s[nb] = __builtin_amdgcn_mfma_f32_16x16x32_bf16(
                        kf[nb], bq, (f32x4){0.f,0.f,0.f,0.f}, 0, 0, 0);
        STAGE(0, 0);
        STAGE(1, 1);
        #pragma unroll
        for (int nb = 0; nb < 4; ++nb)
            kf[nb] = *(const bf16x8*)(kbase + (size_t)(64 + nb*16)*DD);
        SMAX(s, paA);
    }

    for (int n = 0; n < 64; ++n) {
        // S^T(n+1) (kf = K(n+1)), kf <- K(n+2), softmax -> paB  [all private]
        if (n < 63) {
            f32x4 s[4];
            #pragma unroll
            for (int nb = 0; nb < 4; ++nb)
                s[nb] = __builtin_amdgcn_mfma_f32_16x16x32_bf16(
                            kf[nb], bq, (f32x4){0.f,0.f,0.f,0.f}, 0, 0, 0);
            const int j2 = ((n + 2) & 63) * 64;
            #pragma unroll
            for (int nb = 0; nb < 4; ++nb)
                kf[nb] = *(const bf16x8*)(kbase + (size_t)(j2 + nb*16)*DD);
            SMAX(s, paB);
        }

        // staging(n) complete everywhere; 12 newest (stage n+1 + K n+2) stay
        bar_vm12();

        // PV(n): 32 conflict-free ds_read_b128 + 32 MFMA, all per-wave
        const char* bufp = vsm + (n & 1)*32768;
        __builtin_amdgcn_s_setprio(1);
        #pragma unroll
        for (int st = 0; st < 32; ++st) {
            const int cb = st & 15;          // ks = st>>4
            const bf16x8 vfr = *(const bf16x8*)(bufp + st*1024 + lane*16);
            o[cb] = __builtin_amdgcn_mfma_f32_16x16x32_bf16(
                        paA[st >> 4], vfr, o[cb], 0, 0, 0);
        }
        __builtin_amdgcn_s_setprio(0);

        bar_plain();                 // all waves done reading buf[n&1]
        STAGE((n + 2) & 63, n & 1);  // refill just-freed buffer (2 iters ahead)

        paA[0] = paB[0];
        paA[1] = paB[1];
    }

    // l per lane: q=ln, keys {16nb+4quad+r} -> fold r, reduce quad copies
    float lp = (lpq[0] + lpq[1]) + (lpq[2] + lpq[3]);
    lp += __shfl_xor(lp, 16);
    lp += __shfl_xor(lp, 32);
    f32x4 ri;
    #pragma unroll
    for (int r = 0; r < 4; ++r)
        ri[r] = 1.0f / __shfl(lp, quad*4 + r);

    // epilogue: fully private, direct stores (row q = i0+w*16+quad*4+r, col c)
    #pragma unroll
    for (int cb = 0; cb < 16; ++cb) {
        const int c = cb*16 + ln;
        float4 val = make_float4(o[cb][0]*ri[0], o[cb][1]*ri[1],
                                 o[cb][2]*ri[2], o[cb][3]*ri[3]);
        *(float4*)(op + (size_t)c*SS + i0 + w*16 + quad*4) = val;
    }
    #undef STAGE
    #undef SMAX
}

// ------------------------------------------------- launch
extern "C" void kernel_launch(void* const* d_in, const int* in_sizes, int n_in,
                              void* d_out, int out_size, void* d_ws, size_t ws_size,
                              hipStream_t stream)
{
    const float* x  = (const float*)d_in[0];
    const float* y  = (const float*)d_in[1];
    const float* Wq = (const float*)d_in[2];
    const float* bq = (const float*)d_in[3];
    const float* Wk = (const float*)d_in[4];
    const float* bk = (const float*)d_in[5];
    const float* Wv = (const float*)d_in[6];
    const float* bv = (const float*)d_in[7];
    float* out = (float*)d_out;
    bf16* ws   = (bf16*)d_ws;

    bf16* qw = ws + Q_OFF;
    bf16* kw = ws + K_OFF;
    bf16* vw = ws + V_OFF;
    bf16* wb = ws + WB_OFF;

    convert_w_kernel  <<<40,  256, 0, stream>>>(Wq, Wk, Wv, wb);
    transpose_x_kernel<<<512, 256, 0, stream>>>(x, y, vw);
    proj_all_kernel   <<<512, 256, 0, stream>>>(vw, wb, bq, bk, bv, qw, kw, vw);
    attn_kernel       <<<512, 256, 0, stream>>>(qw, kw, vw, out);
}

// Round 11
// 216.876 us; speedup vs baseline: 1.0828x; 1.0274x over previous
//
#include <hip/hip_runtime.h>

#define BB 4
#define CC 256
#define DD 32
#define SS 4096

typedef __bf16 bf16;
typedef __bf16 bf16x8 __attribute__((ext_vector_type(8)));
typedef __bf16 bf16x4 __attribute__((ext_vector_type(4)));
typedef float f32x4 __attribute__((ext_vector_type(4)));
typedef unsigned int u32;
typedef u32 u32x4 __attribute__((ext_vector_type(4)));
typedef unsigned short u16;

// workspace layout (bf16 elements):
//  q:  [2][BB][SS][DD]  off 0         (pos-major, 32 d inner)
//  k:  [2][BB][SS][DD]  off 1048576
//  v:  [2][BB][...]     off 2097152   chunked B-frag order: V[c][key] at
//       (2*(key>>6) + ks)*8192 + (c>>4)*512 + (quadf*16 + (c&15))*8 + j
//       (kk=key&63, ks=kk>>5, quadf=(kk>>2)&3, j=((kk>>4)&1)*4+(kk&3));
//       each 1 KB fragment lane-contiguous; each 32 KB chunk contiguous.
//       TRANSIENT ALIAS: prep writes X^T A-frag tiles here first; proj block
//       (dirb,tile) DMA-reads slice [tile*16384,+16384) into LDS, then
//       overwrites exactly that slice with V output (slice-exact, safe).
//  wb: [320][CC]        off 10485760  (bf16 Wq|Wk|Wv stacked)
#define Q_OFF  0
#define K_OFF  1048576
#define V_OFF  2097152
#define WB_OFF 10485760
#define CH_ELEM 16384   // elements per 64-key V chunk / per X^T tile (32 KB)

static __device__ __forceinline__ u32 pack2(float lo, float hi) {
    bf16 a = (bf16)lo, b = (bf16)hi;
    u16 ua = __builtin_bit_cast(u16, a), ub = __builtin_bit_cast(u16, b);
    return (u32)ua | ((u32)ub << 16);
}

// staged-buffer barrier: wait until only the 12 newest VMEM ops (next chunk's
// 8 staging + the K prefetch quad) remain in flight (T4 counted-vmcnt).
static __device__ __forceinline__ void bar_vm12() {
    asm volatile("s_waitcnt vmcnt(12)" ::: "memory");
    __builtin_amdgcn_s_barrier();
    asm volatile("" ::: "memory");
}
static __device__ __forceinline__ void bar_plain() {
    asm volatile("" ::: "memory");
    __builtin_amdgcn_s_barrier();
    asm volatile("" ::: "memory");
}

// ------------------------------------------------- prep: W fp32->bf16 + X^T tiles
// Blocks 0..511: transpose (src,b,tile) X fp32 -> bf16 A-frag tile into the
// V region (transient alias). Blocks 512..551: convert W -> wb [320][256].
__global__ __launch_bounds__(256) void prep_kernel(
    const float* __restrict__ x, const float* __restrict__ y,
    const float* __restrict__ Wq, const float* __restrict__ Wk,
    const float* __restrict__ Wv,
    bf16* __restrict__ xb, bf16* __restrict__ wb)
{
    const int t   = threadIdx.x;
    const int bid = blockIdx.x;

    if (bid >= 512) {
        const int gid = (bid - 512)*256 + t;         // 40 blocks -> 10240
        const int idx = gid*8;
        const int o = idx >> 8, cc = idx & 255;
        const float* row = (o < 32) ? (Wq + (size_t)o*CC)
                         : (o < 64) ? (Wk + (size_t)(o-32)*CC)
                                    : (Wv + (size_t)(o-64)*CC);
        const float4 a = *(const float4*)(row + cc);
        const float4 c = *(const float4*)(row + cc + 4);
        bf16x8 pk;
        pk[0]=(bf16)a.x; pk[1]=(bf16)a.y; pk[2]=(bf16)a.z; pk[3]=(bf16)a.w;
        pk[4]=(bf16)c.x; pk[5]=(bf16)c.y; pk[6]=(bf16)c.z; pk[7]=(bf16)c.w;
        *(bf16x8*)(wb + idx) = pk;
        return;
    }

    // transpose: element (pos,cc) -> tile*16384 + (pos>>4)*4096 + (cc>>5)*512
    // + ((cc>>3)&3)*128 + (pos&15)*8 + (cc&7)   (pos within 64-tile)
    const int dirb = bid & 7;
    const int src  = dirb >> 2;
    const int b    = dirb & 3;
    const int tile = bid >> 3;                    // 0..63
    const float* in = (src ? y : x) + (size_t)b*CC*SS;
    bf16* outp = xb + (size_t)dirb*1048576 + (size_t)tile*CH_ELEM;

    const int pg = t & 15;          // pos = tile*64 + pg*4 + p
    const int cg = t >> 4;          // cc0 = outer*128 + cg*8
    #pragma unroll
    for (int outer = 0; outer < 2; ++outer) {
        const int cc0 = outer*128 + cg*8;
        float4 v4[8];
        #pragma unroll
        for (int j = 0; j < 8; ++j)
            v4[j] = *(const float4*)(in + (size_t)(cc0 + j)*SS + tile*64 + pg*4);
        #pragma unroll
        for (int p = 0; p < 4; ++p) {
            const int pos = pg*4 + p;             // within tile
            bf16x8 pk;
            #pragma unroll
            for (int j = 0; j < 8; ++j) {
                const float fv = (p==0)?v4[j].x:(p==1)?v4[j].y:(p==2)?v4[j].z:v4[j].w;
                pk[j] = (bf16)fv;
            }
            *(bf16x8*)(outp + (pos>>4)*4096 + (cc0>>5)*512
                       + ((cc0>>3)&3)*128 + (pos&15)*8) = pk;
        }
    }
}

// ------------------------------------------------- fused q,k,v projection (MFMA)
// C[pos][o] = sum_cc X[cc][pos]*W[o][cc] + bias;  o: 0-31 q, 32-63 k, 64-319 v
// X^T tile (64 pos x 256 cc, A-frag order) DMA-staged to LDS in one shot
// (global_load_lds x8/thread), ONE barrier, then 8 chunks x 20 MFMA per wave
// straight through (conflict-free ds_read_b128, W prefetched from L2).
// Reads its xb slice from the V region and overwrites the SAME slice with V.
__global__ __launch_bounds__(256, 2) void proj_all_kernel(
    const bf16* __restrict__ xb, const bf16* __restrict__ wb,
    const float* __restrict__ bq, const float* __restrict__ bk,
    const float* __restrict__ bv,
    bf16* __restrict__ qout, bf16* __restrict__ kout, bf16* __restrict__ vout)
{
    __shared__ __align__(16) char xsm[32768];

    const int t    = threadIdx.x;
    const int lane = t & 63;
    const int w    = t >> 6;
    const int ln   = lane & 15;
    const int quad = lane >> 4;

    const int bid  = blockIdx.x;
    const int dirb = bid & 7;
    const int src  = dirb >> 2;
    const int b    = dirb & 3;
    const int tile = bid >> 3;
    const int i0   = tile * 64;

    // DMA stage the whole X^T tile (32 KB, linear)
    {
        const bf16* xstage = xb + (size_t)dirb*1048576 + (size_t)tile*CH_ELEM
                             + w*512 + lane*8;
        char* ldsb = xsm + w*1024;
        #pragma unroll
        for (int j = 0; j < 8; ++j)
            __builtin_amdgcn_global_load_lds(
                (const __attribute__((address_space(1))) void*)(xstage + j*2048),
                (__attribute__((address_space(3))) void*)(ldsb + j*4096),
                16, 0, 0);
    }

    float bias[5];
    #pragma unroll
    for (int nbl = 0; nbl < 5; ++nbl) {
        const int o = 80*w + nbl*16 + ln;
        bias[nbl] = (o < 32) ? bq[o] : (o < 64) ? bk[o-32] : bv[o-64];
    }
    const bf16* wrow = wb + (size_t)(80*w + ln)*CC + quad*8;
    bf16x8 bf[5];
    #pragma unroll
    for (int nbl = 0; nbl < 5; ++nbl)
        bf[nbl] = *(const bf16x8*)(wrow + (size_t)nbl*16*CC);

    f32x4 acc[4][5];
    #pragma unroll
    for (int mb = 0; mb < 4; ++mb)
        #pragma unroll
        for (int nbl = 0; nbl < 5; ++nbl)
            acc[mb][nbl] = (f32x4){bias[nbl], bias[nbl], bias[nbl], bias[nbl]};

    __syncthreads();   // DMA complete (vmcnt(0) drain is fine here: one-shot)

    for (int n = 0; n < 8; ++n) {
        bf16x8 af[4];
        #pragma unroll
        for (int mb = 0; mb < 4; ++mb)
            af[mb] = *(const bf16x8*)(xsm + mb*8192 + n*1024 + lane*16);
        #pragma unroll
        for (int mb = 0; mb < 4; ++mb)
            #pragma unroll
            for (int nbl = 0; nbl < 5; ++nbl)
                acc[mb][nbl] = __builtin_amdgcn_mfma_f32_16x16x32_bf16(
                                   af[mb], bf[nbl], acc[mb][nbl], 0, 0, 0);
        // prefetch next W chunk (wrap at tail: redundant, in-bounds)
        const int ccn = ((n+1)*32) & 255;
        #pragma unroll
        for (int nbl = 0; nbl < 5; ++nbl)
            bf[nbl] = *(const bf16x8*)(wrow + (size_t)nbl*16*CC + ccn);
    }

    bf16* qo = qout + (size_t)(src*BB + b)*SS*DD;
    bf16* ko = kout + (size_t)(src*BB + b)*SS*DD;
    bf16* vo = vout + (size_t)(src*BB + b)*CC*SS;
    const int n0 = tile;
    #pragma unroll
    for (int nbl = 0; nbl < 5; ++nbl) {
        const int o = 80*w + nbl*16 + ln;
        if (o < 32) {
            #pragma unroll
            for (int mb = 0; mb < 4; ++mb)
                #pragma unroll
                for (int r = 0; r < 4; ++r)
                    qo[(size_t)(i0 + mb*16 + quad*4 + r)*DD + o] = (bf16)acc[mb][nbl][r];
        } else if (o < 64) {
            #pragma unroll
            for (int mb = 0; mb < 4; ++mb)
                #pragma unroll
                for (int r = 0; r < 4; ++r)
                    ko[(size_t)(i0 + mb*16 + quad*4 + r)*DD + (o-32)] = (bf16)acc[mb][nbl][r];
        } else {
            const int c = o - 64;
            const int cb = c >> 4, cl = c & 15;
            // pos = i0+mb*16+quad*4+r -> chunk n0, ks=mb>>1, j=(mb&1)*4+r,
            // quadf=quad -> contiguous bf16x4 store within lane's 16B slot
            #pragma unroll
            for (int mb = 0; mb < 4; ++mb) {
                bf16x4 pk;
                #pragma unroll
                for (int r = 0; r < 4; ++r) pk[r] = (bf16)acc[mb][nbl][r];
                *(bf16x4*)(vo + (size_t)(2*n0 + (mb>>1))*8192 + cb*512
                              + (quad*16 + cl)*8 + (mb&1)*4) = pk;
            }
        }
    }
}

// ------------------------------------------------- attention (LDS-staged V, private P)
// R7/R10 verified structure, loop REORDERED so SMAX is off the critical path:
// bar_vm12 -> PV(n) [ds_read+MFMA issue immediately] -> S^T(n+1) -> bar_plain
// -> STAGE(n+2) -> SMAX(n+1). In-order issue previously forced PV's ds_reads
// to wait behind ~120 VALU ops (16 exp2) with no consumer until next iter;
// now SMAX executes in the shadow of the next staging wait. paA single-
// buffered (PV(n) completes before SMAX overwrites). vmcnt(12) audit: at
// bar_vm12(n) the 12 newest VM ops are stage(n+1)[8]+K(n+2)[4], stage(n) is
// older -> drained; the wrapped K/STAGE at n=62 keep the count exact.
#define L2E   1.4426950408889634f
#define SM_C  (16.0f * L2E)

__global__ __launch_bounds__(256, 2) void attn_kernel(
    const bf16* __restrict__ qg, const bf16* __restrict__ kg,
    const bf16* __restrict__ vg, float* __restrict__ out)
{
    __shared__ __align__(16) char vsm[2*32768];   // V chunk double buffer

    const int t    = threadIdx.x;
    const int lane = t & 63;
    const int w    = t >> 6;
    const int ln   = lane & 15;
    const int quad = lane >> 4;

    const int bid  = blockIdx.x;
    const int dirb = bid & 7;              // one (dir,b) per XCD -> V L2-resident
    const int dir  = dirb >> 2;
    const int b    = dirb & 3;
    const int i0   = (bid >> 3) * 64;

    const bf16* q = qg + ((size_t)dir*BB + b)*SS*DD;
    const bf16* k = kg + ((size_t)(1-dir)*BB + b)*SS*DD;
    const bf16* v = vg + ((size_t)(1-dir)*BB + b)*(size_t)CC*SS;
    float* op = out + ((size_t)dir*BB + b)*(size_t)CC*SS;

    // Q B-frag: B[n=q(ln)][k=d(quad*8+)] — wave's 16 queries
    const bf16x8 bq = *(const bf16x8*)(q + (size_t)(i0 + w*16 + ln)*DD + quad*8);
    // K A-frag base: A[m=key(ln)][k=d(quad*8+)]
    const bf16* kbase = k + (size_t)ln*DD + quad*8;
    // staging: thread t copies 8x16B, linear
    const bf16* vstage = v + w*512 + lane*8;
    char* lds0 = vsm + w*1024;

    f32x4 o[16];
    #pragma unroll
    for (int cb = 0; cb < 16; ++cb) o[cb] = (f32x4){0.f,0.f,0.f,0.f};
    f32x4 lpq = (f32x4){0.f,0.f,0.f,0.f};

    bf16x8 kf[4];
    #pragma unroll
    for (int nb = 0; nb < 4; ++nb)
        kf[nb] = *(const bf16x8*)(kbase + (size_t)(nb*16)*DD);

    #define STAGE(ch, buf) do {                                               \
        const bf16* gp_ = vstage + (size_t)(ch)*CH_ELEM;                      \
        char* lp_ = lds0 + (buf)*32768;                                       \
        _Pragma("unroll")                                                     \
        for (int j = 0; j < 8; ++j)                                           \
            __builtin_amdgcn_global_load_lds(                                 \
                (const __attribute__((address_space(1))) void*)(gp_ + j*2048),\
                (__attribute__((address_space(3))) void*)(lp_ + j*4096),      \
                16, 0, 0);                                                    \
    } while (0)

    #define SMAX(sarr, pa) do {                                               \
        float e_[4][4];                                                       \
        _Pragma("unroll")                                                     \
        for (int nb = 0; nb < 4; ++nb)                                        \
            _Pragma("unroll")                                                 \
            for (int r = 0; r < 4; ++r) {                                     \
                e_[nb][r] = exp2f((sarr)[nb][r]*L2E - SM_C);                   \
                lpq[r] += e_[nb][r];                                          \
            }                                                                 \
        _Pragma("unroll")                                                     \
        for (int ks = 0; ks < 2; ++ks) {                                      \
            u32x4 pk_;                                                        \
            _Pragma("unroll")                                                 \
            for (int jp = 0; jp < 4; ++jp)                                    \
                pk_[jp] = pack2(e_[2*ks + (jp>>1)][2*(jp&1)],                 \
                                e_[2*ks + (jp>>1)][2*(jp&1) + 1]);            \
            (pa)[ks] = __builtin_bit_cast(bf16x8, pk_);                       \
        }                                                                     \
    } while (0)

    bf16x8 paA[2];
    // prologue: S^T(0) -> paA; stage chunks 0,1; kf <- K(1)
    {
        f32x4 s[4];
        #pragma unroll
        for (int nb = 0; nb < 4; ++nb)
            s[nb] = __builtin_amdgcn_mfma_f32_16x16x32_bf16(
                        kf[nb], bq, (f32x4){0.f,0.f,0.f,0.f}, 0, 0, 0);
        STAGE(0, 0);
        STAGE(1, 1);
        #pragma unroll
        for (int nb = 0; nb < 4; ++nb)
            kf[nb] = *(const bf16x8*)(kbase + (size_t)(64 + nb*16)*DD);
        SMAX(s, paA);
    }

    for (int n = 0; n < 64; ++n) {
        // staging(n) complete everywhere; 12 newest (stage n+1 + K n+2) stay
        bar_vm12();

        // PV(n) FIRST: 32 conflict-free ds_read_b128 + 32 MFMA (paA from n-1's
        // SMAX) — issues immediately after the barrier, no VALU prefix
        const char* bufp = vsm + (n & 1)*32768;
        __builtin_amdgcn_s_setprio(1);
        #pragma unroll
        for (int st = 0; st < 32; ++st) {
            const int cb = st & 15;          // ks = st>>4
            const bf16x8 vfr = *(const bf16x8*)(bufp + st*1024 + lane*16);
            o[cb] = __builtin_amdgcn_mfma_f32_16x16x32_bf16(
                        paA[st >> 4], vfr, o[cb], 0, 0, 0);
        }
        __builtin_amdgcn_s_setprio(0);

        // S^T(n+1) (kf = K(n+1)) + K(n+2) prefetch — MFMA queued behind PV
        f32x4 s[4];
        if (n < 63) {
            #pragma unroll
            for (int nb = 0; nb < 4; ++nb)
                s[nb] = __builtin_amdgcn_mfma_f32_16x16x32_bf16(
                            kf[nb], bq, (f32x4){0.f,0.f,0.f,0.f}, 0, 0, 0);
            const int j2 = ((n + 2) & 63) * 64;
            #pragma unroll
            for (int nb = 0; nb < 4; ++nb)
                kf[nb] = *(const bf16x8*)(kbase + (size_t)(j2 + nb*16)*DD);
        }

        bar_plain();                 // all waves done reading buf[n&1]
        if (n < 63)
            STAGE((n + 2) & 63, n & 1);  // refill just-freed buffer

        // SMAX(n+1) -> paA, in the shadow of the next staging wait
        if (n < 63)
            SMAX(s, paA);
    }

    // l per lane: q=ln, keys {16nb+4quad+r} -> fold r, reduce quad copies
    float lp = (lpq[0] + lpq[1]) + (lpq[2] + lpq[3]);
    lp += __shfl_xor(lp, 16);
    lp += __shfl_xor(lp, 32);
    f32x4 ri;
    #pragma unroll
    for (int r = 0; r < 4; ++r)
        ri[r] = 1.0f / __shfl(lp, quad*4 + r);

    // epilogue: fully private, direct stores (row q = i0+w*16+quad*4+r, col c)
    #pragma unroll
    for (int cb = 0; cb < 16; ++cb) {
        const int c = cb*16 + ln;
        float4 val = make_float4(o[cb][0]*ri[0], o[cb][1]*ri[1],
                                 o[cb][2]*ri[2], o[cb][3]*ri[3]);
        *(float4*)(op + (size_t)c*SS + i0 + w*16 + quad*4) = val;
    }
    #undef STAGE
    #undef SMAX
}

// ------------------------------------------------- launch
extern "C" void kernel_launch(void* const* d_in, const int* in_sizes, int n_in,
                              void* d_out, int out_size, void* d_ws, size_t ws_size,
                              hipStream_t stream)
{
    const float* x  = (const float*)d_in[0];
    const float* y  = (const float*)d_in[1];
    const float* Wq = (const float*)d_in[2];
    const float* bq = (const float*)d_in[3];
    const float* Wk = (const float*)d_in[4];
    const float* bk = (const float*)d_in[5];
    const float* Wv = (const float*)d_in[6];
    const float* bv = (const float*)d_in[7];
    float* out = (float*)d_out;
    bf16* ws   = (bf16*)d_ws;

    bf16* qw = ws + Q_OFF;
    bf16* kw = ws + K_OFF;
    bf16* vw = ws + V_OFF;
    bf16* wb = ws + WB_OFF;

    prep_kernel     <<<552, 256, 0, stream>>>(x, y, Wq, Wk, Wv, vw, wb);
    proj_all_kernel <<<512, 256, 0, stream>>>(vw, wb, bq, bk, bv, qw, kw, vw);
    attn_kernel     <<<512, 256, 0, stream>>>(qw, kw, vw, out);
}